// Round 6
// baseline (120.373 us; speedup 1.0000x reference)
//
#include <hip/hip_runtime.h>
#include <math.h>

#define N_NODES 50000
#define DEG 16
#define E_EDGES (N_NODES * DEG)
#define FIN 128
#define FTOT 192   // 2*FQK + FV
#define FQK 64
#define FV 64
#define H 8

typedef __attribute__((ext_vector_type(8))) short short8;
typedef __attribute__((ext_vector_type(4))) float float4v;

__device__ inline unsigned short f2bf(float f) {
    unsigned int u = __float_as_uint(f);
    unsigned int r = u + 0x7fffu + ((u >> 16) & 1u);  // RNE
    return (unsigned short)(r >> 16);
}
__device__ inline float bflo(unsigned int w) { return __uint_as_float(w << 16); }
__device__ inline float bfhi(unsigned int w) { return __uint_as_float(w & 0xffff0000u); }

#define LDB 136   // 128 + 8 bf16 pad (row stride of the Wt LDS image)
#define LDC 194   // 192 + 2 bf16 pad for the epilogue transpose

// ---------- prep: Wt (padded LDS image) [n][LDB], n<192, k<128 ----------
__global__ void wt_prep(const float* __restrict__ W, unsigned short* __restrict__ Wt) {
    int t = blockIdx.x * 256 + threadIdx.x;
    if (t >= FIN * FTOT) return;
    int k = t / FTOT, n = t % FTOT;          // coalesced read of W
    Wt[n * LDB + k] = f2bf(W[t]);
}

// ---------- GEMM: qkv(bf16, kv-interleaved) = x @ W via MFMA ----------
// Block: 256 thr = 4 waves, 64 rows. Full K=128, full N=192 per block.
__global__ __launch_bounds__(256) void gemm_qkv(const float* __restrict__ x,
                                                const unsigned short* __restrict__ Wt,
                                                unsigned short* __restrict__ qkv) {
    __shared__ unsigned short Bt[FTOT * LDB];           // 52224 B
    unsigned short* Ct = Bt;                            // reused after MFMAs
    const int tid = threadIdx.x;
    const int wave = tid >> 6, lane = tid & 63;
    const int m = lane & 15, q = lane >> 4;
    const int row = blockIdx.x * 64 + wave * 16 + m;
    const int rowc = min(row, N_NODES - 1);

    // issue ALL x loads first (nontemporal: x has no reuse) so they overlap staging
    const float* xr = x + rowc * FIN;
    float4v f[8];
#pragma unroll
    for (int s = 0; s < 4; s++) {
        f[2 * s]     = __builtin_nontemporal_load((const float4v*)(xr + s * 32 + q * 8));
        f[2 * s + 1] = __builtin_nontemporal_load((const float4v*)(xr + s * 32 + q * 8 + 4));
    }

    // stage padded Wt image -> LDS: 3264 uint4 chunks
#pragma unroll
    for (int i = 0; i < 13; i++) {
        int c = tid + i * 256;
        if (c < (FTOT * LDB) / 8)
            *(uint4*)(&Bt[c * 8]) = *(const uint4*)(Wt + c * 8);
    }

    // convert A fragments (x loads have drained by now)
    short8 a[4];
#pragma unroll
    for (int s = 0; s < 4; s++) {
        short8 av;
        av[0] = (short)f2bf(f[2*s].x); av[1] = (short)f2bf(f[2*s].y);
        av[2] = (short)f2bf(f[2*s].z); av[3] = (short)f2bf(f[2*s].w);
        av[4] = (short)f2bf(f[2*s+1].x); av[5] = (short)f2bf(f[2*s+1].y);
        av[6] = (short)f2bf(f[2*s+1].z); av[7] = (short)f2bf(f[2*s+1].w);
        a[s] = av;
    }
    __syncthreads();

    float4v acc[12];
#pragma unroll
    for (int ct = 0; ct < 12; ct++) acc[ct] = (float4v){0.f, 0.f, 0.f, 0.f};
#pragma unroll
    for (int ct = 0; ct < 12; ct++) {
#pragma unroll
        for (int s = 0; s < 4; s++) {
            short8 b = *(const short8*)(&Bt[(ct * 16 + m) * LDB + s * 32 + q * 8]);
            acc[ct] = __builtin_amdgcn_mfma_f32_16x16x32_bf16(a[s], b, acc[ct], 0, 0, 0);
        }
    }
    __syncthreads();   // all Bt reads done; safe to reuse as Ct

    // transpose into interleaved-layout LDS tile (q pre-scaled)
    const int lrow0 = wave * 16 + q * 4;
#pragma unroll
    for (int ct = 0; ct < 12; ct++) {
        const int col = ct * 16 + m;
        int off; float scale;
        if (col < FQK)          { off = col;                      scale = 0.35355339059327373f; }
        else if (col < 2 * FQK) { off = 64 + 2 * (col - 64);      scale = 1.f; }  // k
        else                    { off = 64 + 2 * (col - 128) + 1; scale = 1.f; }  // v
#pragma unroll
        for (int i = 0; i < 4; i++)
            Ct[(lrow0 + i) * LDC + off] = f2bf(acc[ct][i] * scale);
    }
    __syncthreads();

    // coalesced store: 64 rows x 96 dwords (keep cached: attn reads these next)
    unsigned int* qg = (unsigned int*)qkv;
    const int base = blockIdx.x * 64;
#pragma unroll
    for (int i = 0; i < 24; i++) {
        int l = tid + i * 256;
        int r = l / 96, dw = l - r * 96;
        if (base + r < N_NODES)
            qg[(size_t)(base + r) * 96 + dw] = *(const unsigned int*)(&Ct[r * LDC + 2 * dw]);
    }
}

// ---------- attention: one wave/node; 4 quarter-waves each own 4 edges ----------
// lane = 16*quarter + l; lane owns kv-pair slots 4l..4l+3 (head h = l>>1).
__global__ __launch_bounds__(256) void attn(const unsigned short* __restrict__ qkv,
                                            const int* __restrict__ dest,
                                            float* __restrict__ out) {
    const int node = blockIdx.x * 4 + (threadIdx.x >> 6);
    const int lane = threadIdx.x & 63;
    const int quarter = lane >> 4;
    const int l = lane & 15;
    if (node >= N_NODES) return;  // wave-uniform

    // dest first: it heads the serial dest->kv dependency chain
    const int4 dd = ((const int4*)(dest + (size_t)node * DEG))[quarter];
    // q slots 4l..4l+3 (pre-scaled); independent of dd, overlaps it
    const uint2 qw = *(const uint2*)(qkv + node * FTOT + 4 * l);

    uint4 kv[4];
    kv[0] = *(const uint4*)(qkv + dd.x * FTOT + 64 + 8 * l);
    kv[1] = *(const uint4*)(qkv + dd.y * FTOT + 64 + 8 * l);
    kv[2] = *(const uint4*)(qkv + dd.z * FTOT + 64 + 8 * l);
    kv[3] = *(const uint4*)(qkv + dd.w * FTOT + 64 + 8 * l);

    const float q0 = bflo(qw.x), q1 = bfhi(qw.x);
    const float q2 = bflo(qw.y), q3 = bfhi(qw.y);

    float lg[4];
#pragma unroll
    for (int t = 0; t < 4; t++) {
        float p = q0 * bflo(kv[t].x);
        p = fmaf(q1, bflo(kv[t].y), p);
        p = fmaf(q2, bflo(kv[t].z), p);
        p = fmaf(q3, bflo(kv[t].w), p);
        p += __shfl_xor(p, 1, 64);        // pair (2h, 2h+1): full 8-dim dot
        lg[t] = p;
    }

    // global max per head across all 16 edges
    float m = fmaxf(fmaxf(lg[0], lg[1]), fmaxf(lg[2], lg[3]));
    m = fmaxf(m, __shfl_xor(m, 16, 64));
    m = fmaxf(m, __shfl_xor(m, 32, 64));

    float s = 0.f, o0 = 0.f, o1 = 0.f, o2 = 0.f, o3 = 0.f;
#pragma unroll
    for (int t = 0; t < 4; t++) {
        const float p = __expf(lg[t] - m);
        s += p;
        o0 = fmaf(p, bfhi(kv[t].x), o0);
        o1 = fmaf(p, bfhi(kv[t].y), o1);
        o2 = fmaf(p, bfhi(kv[t].z), o2);
        o3 = fmaf(p, bfhi(kv[t].w), o3);
    }
    // merge the 4 quarters
    s  += __shfl_xor(s, 16, 64);  s  += __shfl_xor(s, 32, 64);
    o0 += __shfl_xor(o0, 16, 64); o0 += __shfl_xor(o0, 32, 64);
    o1 += __shfl_xor(o1, 16, 64); o1 += __shfl_xor(o1, 32, 64);
    o2 += __shfl_xor(o2, 16, 64); o2 += __shfl_xor(o2, 32, 64);
    o3 += __shfl_xor(o3, 16, 64); o3 += __shfl_xor(o3, 32, 64);

    if (quarter == 0) {
        const float inv = 1.0f / s;
        float4v r; r.x = o0 * inv; r.y = o1 * inv; r.z = o2 * inv; r.w = o3 * inv;
        __builtin_nontemporal_store(r, (float4v*)(out + node * 64 + 4 * l));
    }
}

extern "C" void kernel_launch(void* const* d_in, const int* in_sizes, int n_in,
                              void* d_out, int out_size, void* d_ws, size_t ws_size,
                              hipStream_t stream) {
    const float* x = (const float*)d_in[0];
    const float* W = (const float*)d_in[1];
    // d_in[2] = batch (unused by reference)
    const int* ei = (const int*)d_in[3];
    const int* dest = ei + E_EDGES;  // ei[1]
    float* out = (float*)d_out;

    unsigned short* qkv = (unsigned short*)d_ws;                       // 19.2 MB
    unsigned short* Wt  = (unsigned short*)((char*)d_ws + 19200000);   // 52.2 KB (padded image)

    wt_prep<<<(FIN * FTOT + 255) / 256, 256, 0, stream>>>(W, Wt);
    gemm_qkv<<<(N_NODES + 63) / 64, 256, 0, stream>>>(x, Wt, qkv);
    attn<<<(N_NODES + 3) / 4, 256, 0, stream>>>(qkv, dest, out);
}

// Round 7
// 117.320 us; speedup vs baseline: 1.0260x; 1.0260x over previous
//
#include <hip/hip_runtime.h>
#include <math.h>

#define N_NODES 50000
#define DEG 16
#define E_EDGES (N_NODES * DEG)
#define FIN 128
#define FTOT 192   // 2*FQK + FV
#define FQK 64
#define FV 64
#define H 8

typedef __attribute__((ext_vector_type(8))) short short8;
typedef __attribute__((ext_vector_type(4))) float float4v;

__device__ inline unsigned short f2bf(float f) {
    unsigned int u = __float_as_uint(f);
    unsigned int r = u + 0x7fffu + ((u >> 16) & 1u);  // RNE
    return (unsigned short)(r >> 16);
}
__device__ inline float bflo(unsigned int w) { return __uint_as_float(w << 16); }
__device__ inline float bfhi(unsigned int w) { return __uint_as_float(w & 0xffff0000u); }

#define LDB 136   // 128 + 8 bf16 pad (row stride of the Wt LDS image)
#define LDC 194   // 192 + 2 bf16 pad for the epilogue transpose

// ---------- prep: Wt (padded LDS image) [n][LDB], n<192, k<128 ----------
__global__ void wt_prep(const float* __restrict__ W, unsigned short* __restrict__ Wt) {
    int t = blockIdx.x * 256 + threadIdx.x;
    if (t >= FIN * FTOT) return;
    int k = t / FTOT, n = t % FTOT;          // coalesced read of W
    Wt[n * LDB + k] = f2bf(W[t]);
}

// ---------- GEMM: qkv(bf16, kv-interleaved) = x @ W via MFMA ----------
// Block: 256 thr = 4 waves, 64 rows. Full K=128, full N=192 per block.
__global__ __launch_bounds__(256) void gemm_qkv(const float* __restrict__ x,
                                                const unsigned short* __restrict__ Wt,
                                                unsigned short* __restrict__ qkv) {
    __shared__ unsigned short Bt[FTOT * LDB];           // 52224 B
    unsigned short* Ct = Bt;                            // reused after MFMAs
    const int tid = threadIdx.x;

    // stage padded Wt image -> LDS: 3264 uint4 chunks
#pragma unroll
    for (int i = 0; i < 13; i++) {
        int c = tid + i * 256;
        if (c < (FTOT * LDB) / 8)
            *(uint4*)(&Bt[c * 8]) = *(const uint4*)(Wt + c * 8);
    }

    const int wave = tid >> 6, lane = tid & 63;
    const int m = lane & 15, q = lane >> 4;
    const int row = blockIdx.x * 64 + wave * 16 + m;
    const int rowc = min(row, N_NODES - 1);

    // A fragments: lane holds x[row][ s*32 + q*8 .. +7 ]
    short8 a[4];
    const float* xr = x + rowc * FIN;
#pragma unroll
    for (int s = 0; s < 4; s++) {
        float4v f0 = *(const float4v*)(xr + s * 32 + q * 8);
        float4v f1 = *(const float4v*)(xr + s * 32 + q * 8 + 4);
        short8 av;
        av[0] = (short)f2bf(f0.x); av[1] = (short)f2bf(f0.y);
        av[2] = (short)f2bf(f0.z); av[3] = (short)f2bf(f0.w);
        av[4] = (short)f2bf(f1.x); av[5] = (short)f2bf(f1.y);
        av[6] = (short)f2bf(f1.z); av[7] = (short)f2bf(f1.w);
        a[s] = av;
    }
    __syncthreads();

    float4v acc[12];
#pragma unroll
    for (int ct = 0; ct < 12; ct++) acc[ct] = (float4v){0.f, 0.f, 0.f, 0.f};
#pragma unroll
    for (int ct = 0; ct < 12; ct++) {
#pragma unroll
        for (int s = 0; s < 4; s++) {
            short8 b = *(const short8*)(&Bt[(ct * 16 + m) * LDB + s * 32 + q * 8]);
            acc[ct] = __builtin_amdgcn_mfma_f32_16x16x32_bf16(a[s], b, acc[ct], 0, 0, 0);
        }
    }
    __syncthreads();   // all Bt reads done; safe to reuse as Ct

    // transpose into interleaved-layout LDS tile (q pre-scaled)
    const int lrow0 = wave * 16 + q * 4;
#pragma unroll
    for (int ct = 0; ct < 12; ct++) {
        const int col = ct * 16 + m;
        int off; float scale;
        if (col < FQK)          { off = col;                      scale = 0.35355339059327373f; }
        else if (col < 2 * FQK) { off = 64 + 2 * (col - 64);      scale = 1.f; }  // k
        else                    { off = 64 + 2 * (col - 128) + 1; scale = 1.f; }  // v
#pragma unroll
        for (int i = 0; i < 4; i++)
            Ct[(lrow0 + i) * LDC + off] = f2bf(acc[ct][i] * scale);
    }
    __syncthreads();

    // coalesced store: 64 rows x 96 dwords
    unsigned int* qg = (unsigned int*)qkv;
    const int base = blockIdx.x * 64;
#pragma unroll
    for (int i = 0; i < 24; i++) {
        int l = tid + i * 256;
        int r = l / 96, dw = l - r * 96;
        if (base + r < N_NODES)
            qg[(size_t)(base + r) * 96 + dw] = *(const unsigned int*)(&Ct[r * LDC + 2 * dw]);
    }
}

// ---------- attention: each 16-lane quarter fully owns ONE node (wave = 4 nodes) ----------
// lane = 16*quarter + l; lane owns kv-pair slots 4l..4l+3 (head h = l>>1).
// After shfl_xor(1), lanes 2h/2h+1 both hold the full 8-dim head dot, so
// softmax (max/sum/normalize) is pure per-lane register math — no merges.
__global__ __launch_bounds__(256) void attn(const unsigned short* __restrict__ qkv,
                                            const int* __restrict__ dest,
                                            float* __restrict__ out) {
    const int tid = threadIdx.x;
    const int wave = tid >> 6, lane = tid & 63;
    const int quarter = lane >> 4, l = lane & 15;
    const int node = (blockIdx.x * 4 + wave) * 4 + quarter;  // 3125*4*4 = 50000 exact

    // per-lane dest (this quarter's 16 edges, one per lane) and q slots 4l..4l+3
    const int dd = dest[(size_t)node * DEG + l];
    const uint2 qw = *(const uint2*)(qkv + node * FTOT + 4 * l);

    uint4 kv[DEG];
#pragma unroll
    for (int e = 0; e < DEG; e++) {
        const int d = __shfl(dd, (lane & 48) + e, 64);   // broadcast within quarter
        kv[e] = *(const uint4*)(qkv + d * FTOT + 64 + 8 * l);
    }

    const float q0 = bflo(qw.x), q1 = bfhi(qw.x);
    const float q2 = bflo(qw.y), q3 = bfhi(qw.y);

    float lg[DEG];
#pragma unroll
    for (int e = 0; e < DEG; e++) {
        float p = q0 * bflo(kv[e].x);
        p = fmaf(q1, bflo(kv[e].y), p);
        p = fmaf(q2, bflo(kv[e].z), p);
        p = fmaf(q3, bflo(kv[e].w), p);
        p += __shfl_xor(p, 1, 64);        // pair (2h, 2h+1): full 8-dim head dot
        lg[e] = p;
    }

    float m = lg[0];
#pragma unroll
    for (int e = 1; e < DEG; e++) m = fmaxf(m, lg[e]);

    float s = 0.f, o0 = 0.f, o1 = 0.f, o2 = 0.f, o3 = 0.f;
#pragma unroll
    for (int e = 0; e < DEG; e++) {
        const float p = __expf(lg[e] - m);
        s += p;
        o0 = fmaf(p, bfhi(kv[e].x), o0);
        o1 = fmaf(p, bfhi(kv[e].y), o1);
        o2 = fmaf(p, bfhi(kv[e].z), o2);
        o3 = fmaf(p, bfhi(kv[e].w), o3);
    }
    const float inv = 1.0f / s;
    float4v r; r.x = o0 * inv; r.y = o1 * inv; r.z = o2 * inv; r.w = o3 * inv;
    *(float4v*)(out + (size_t)node * 64 + 4 * l) = r;   // 16 lanes x 16B contiguous
}

extern "C" void kernel_launch(void* const* d_in, const int* in_sizes, int n_in,
                              void* d_out, int out_size, void* d_ws, size_t ws_size,
                              hipStream_t stream) {
    const float* x = (const float*)d_in[0];
    const float* W = (const float*)d_in[1];
    // d_in[2] = batch (unused by reference)
    const int* ei = (const int*)d_in[3];
    const int* dest = ei + E_EDGES;  // ei[1]
    float* out = (float*)d_out;

    unsigned short* qkv = (unsigned short*)d_ws;                       // 19.2 MB
    unsigned short* Wt  = (unsigned short*)((char*)d_ws + 19200000);   // 52.2 KB (padded image)

    wt_prep<<<(FIN * FTOT + 255) / 256, 256, 0, stream>>>(W, Wt);
    gemm_qkv<<<(N_NODES + 63) / 64, 256, 0, stream>>>(x, Wt, qkv);
    attn<<<N_NODES / 16, 256, 0, stream>>>(qkv, dest, out);  // 3125 blocks, 4 nodes/wave
}

// Round 8
// 112.614 us; speedup vs baseline: 1.0689x; 1.0418x over previous
//
#include <hip/hip_runtime.h>
#include <math.h>

#define N_NODES 50000
#define DEG 16
#define E_EDGES (N_NODES * DEG)
#define FIN 128
#define FTOT 192   // 2*FQK + FV
#define FQK 64
#define FV 64
#define H 8

typedef __attribute__((ext_vector_type(8))) short short8;
typedef __attribute__((ext_vector_type(4))) float float4v;

__device__ inline unsigned short f2bf(float f) {
    unsigned int u = __float_as_uint(f);
    unsigned int r = u + 0x7fffu + ((u >> 16) & 1u);  // RNE
    return (unsigned short)(r >> 16);
}
__device__ inline float bf2f(unsigned short b) {
    return __uint_as_float(((unsigned int)b) << 16);
}

#define LDB 136   // 128 + 8 bf16 pad (row stride of the B LDS image)
#define LDC 194   // 192 + 2 bf16 pad for the epilogue transpose

// ---------- GEMM: qkv(bf16, kv-interleaved) = x @ W via MFMA ----------
// Block: 256 thr = 4 waves, 64 rows. Full K=128, full N=192 per block.
// W (fp32 [128][192], L2-resident) is converted to the bf16 LDS image in-block:
// no separate wt_prep dispatch.
__global__ __launch_bounds__(256) void gemm_qkv(const float* __restrict__ x,
                                                const float* __restrict__ W,
                                                unsigned short* __restrict__ qkv) {
    __shared__ unsigned short Bt[FTOT * LDB];           // 52224 B
    unsigned short* Ct = Bt;                            // reused after MFMAs
    const int tid = threadIdx.x;

    // stage W -> Bt[n][k] (transposed, bf16): 3072 thread-iters x 8 k-elements
#pragma unroll
    for (int i = 0; i < 12; i++) {
        int idx = tid + i * 256;            // 0..3071
        int n = idx % 192, kg = idx / 192;  // kg 0..15
        int k0 = kg * 8;
        unsigned short tmp[8];
#pragma unroll
        for (int j = 0; j < 8; j++)
            tmp[j] = f2bf(W[(k0 + j) * FTOT + n]);   // lanes sweep n: coalesced
        *(uint4*)(&Bt[n * LDB + k0]) = *(const uint4*)tmp;
    }

    const int wave = tid >> 6, lane = tid & 63;
    const int m = lane & 15, q = lane >> 4;
    const int row = blockIdx.x * 64 + wave * 16 + m;
    const int rowc = min(row, N_NODES - 1);

    // A fragments: lane holds x[row][ s*32 + q*8 .. +7 ]
    short8 a[4];
    const float* xr = x + rowc * FIN;
#pragma unroll
    for (int s = 0; s < 4; s++) {
        float4v f0 = *(const float4v*)(xr + s * 32 + q * 8);
        float4v f1 = *(const float4v*)(xr + s * 32 + q * 8 + 4);
        short8 av;
        av[0] = (short)f2bf(f0.x); av[1] = (short)f2bf(f0.y);
        av[2] = (short)f2bf(f0.z); av[3] = (short)f2bf(f0.w);
        av[4] = (short)f2bf(f1.x); av[5] = (short)f2bf(f1.y);
        av[6] = (short)f2bf(f1.z); av[7] = (short)f2bf(f1.w);
        a[s] = av;
    }
    __syncthreads();

    float4v acc[12];
#pragma unroll
    for (int ct = 0; ct < 12; ct++) acc[ct] = (float4v){0.f, 0.f, 0.f, 0.f};
#pragma unroll
    for (int ct = 0; ct < 12; ct++) {
#pragma unroll
        for (int s = 0; s < 4; s++) {
            short8 b = *(const short8*)(&Bt[(ct * 16 + m) * LDB + s * 32 + q * 8]);
            acc[ct] = __builtin_amdgcn_mfma_f32_16x16x32_bf16(a[s], b, acc[ct], 0, 0, 0);
        }
    }
    __syncthreads();   // all Bt reads done; safe to reuse as Ct

    // transpose into interleaved-layout LDS tile (q pre-scaled)
    const int lrow0 = wave * 16 + q * 4;
#pragma unroll
    for (int ct = 0; ct < 12; ct++) {
        const int col = ct * 16 + m;
        int off; float scale;
        if (col < FQK)          { off = col;                      scale = 0.35355339059327373f; }
        else if (col < 2 * FQK) { off = 64 + 2 * (col - 64);      scale = 1.f; }  // k
        else                    { off = 64 + 2 * (col - 128) + 1; scale = 1.f; }  // v
#pragma unroll
        for (int i = 0; i < 4; i++)
            Ct[(lrow0 + i) * LDC + off] = f2bf(acc[ct][i] * scale);
    }
    __syncthreads();

    // coalesced store: 64 rows x 96 dwords
    unsigned int* qg = (unsigned int*)qkv;
    const int base = blockIdx.x * 64;
#pragma unroll
    for (int i = 0; i < 24; i++) {
        int l = tid + i * 256;
        int r = l / 96, dw = l - r * 96;
        if (base + r < N_NODES)
            qg[(size_t)(base + r) * 96 + dw] = *(const unsigned int*)(&Ct[r * LDC + 2 * dw]);
    }
}

// ---------- attention (R3 half-wave form, best measured): one wave per node ----------
// two wave-halves each process 8 of the 16 edges; lane owns kv-pair slots 2l,2l+1
__global__ __launch_bounds__(256) void attn(const unsigned short* __restrict__ qkv,
                                            const int* __restrict__ dest,
                                            float* __restrict__ out) {
    const int node = blockIdx.x * 4 + (threadIdx.x >> 6);
    const int lane = threadIdx.x & 63;
    const int half = lane >> 5;
    const int l = lane & 31;           // owns slots 2l, 2l+1
    if (node >= N_NODES) return;       // wave-uniform

    const unsigned int qw = *(const unsigned int*)(qkv + node * FTOT + 2 * l);  // pre-scaled q
    const float q0 = __uint_as_float(qw << 16);
    const float q1 = __uint_as_float(qw & 0xffff0000u);
    const int dj = dest[node * DEG + (lane & 15)];

    uint2 kv[8];
#pragma unroll
    for (int t = 0; t < 8; t++) {
        const int d = __shfl(dj, 2 * t + half, 64);
        kv[t] = *(const uint2*)(qkv + d * FTOT + 64 + 4 * l);  // k/v for slots 2l,2l+1
    }

    float lg[8];
#pragma unroll
    for (int t = 0; t < 8; t++) {
        const float k0 = __uint_as_float(kv[t].x << 16);
        const float k1 = __uint_as_float(kv[t].y << 16);
        float p = fmaf(q0, k0, q1 * k1);
        p += __shfl_xor(p, 1, 64);     // reduce over the head's 4 lanes
        p += __shfl_xor(p, 2, 64);
        lg[t] = p;
    }
    float mx = lg[0];
#pragma unroll
    for (int t = 1; t < 8; t++) mx = fmaxf(mx, lg[t]);
    float s = 0.f, o0 = 0.f, o1 = 0.f;
#pragma unroll
    for (int t = 0; t < 8; t++) {
        const float p = __expf(lg[t] - mx);
        s += p;
        o0 = fmaf(p, __uint_as_float(kv[t].x & 0xffff0000u), o0);
        o1 = fmaf(p, __uint_as_float(kv[t].y & 0xffff0000u), o1);
    }
    // merge the two halves (each covered 8 of the 16 edges)
    const float mo = __shfl_xor(mx, 32, 64);
    const float mn = fmaxf(mx, mo);
    const float f = __expf(mx - mn);
    s *= f; o0 *= f; o1 *= f;
    s  += __shfl_xor(s, 32, 64);
    o0 += __shfl_xor(o0, 32, 64);
    o1 += __shfl_xor(o1, 32, 64);
    if (half == 0) {
        float2 r; r.x = o0 / s; r.y = o1 / s;
        *(float2*)(out + node * 64 + 2 * l) = r;
    }
}

extern "C" void kernel_launch(void* const* d_in, const int* in_sizes, int n_in,
                              void* d_out, int out_size, void* d_ws, size_t ws_size,
                              hipStream_t stream) {
    const float* x = (const float*)d_in[0];
    const float* W = (const float*)d_in[1];
    // d_in[2] = batch (unused by reference)
    const int* ei = (const int*)d_in[3];
    const int* dest = ei + E_EDGES;  // ei[1]
    float* out = (float*)d_out;

    unsigned short* qkv = (unsigned short*)d_ws;   // 19.2 MB scratch

    gemm_qkv<<<(N_NODES + 63) / 64, 256, 0, stream>>>(x, W, qkv);
    attn<<<(N_NODES + 3) / 4, 256, 0, stream>>>(qkv, dest, out);
}